// Round 2
// baseline (10130.887 us; speedup 1.0000x reference)
//
#include <hip/hip_runtime.h>
#include <stdint.h>

// FPS: B=16, C=3, N=131072, M=num_points (2048, derived from out_size).
// 256 blocks (16 per batch) x 1024 threads, 1 block/CU, all state in registers.
// Cross-block argmax via tagged u64 slots in d_ws (agent-scope atomics),
// double-buffered by iteration parity (race-free: max 1-iter skew).
//
// Numerics: distance computed as fma(dz,dz, fma(dy,dy, dx*dx)) to bit-match
// the XLA-CPU reference (LLVM contracts the 3-element reduce chain into FMAs;
// fma(dx,dx,0) == rn(dx*dx)). Explicit __builtin_fmaf/__fmul_rn so no
// compiler fp-contract mode can change the op sequence.

#define NBATCH    16
#define NPTS      131072
#define SUBBLOCKS 16
#define NTHREADS  1024
#define PPT       (NPTS / (SUBBLOCKS * NTHREADS))  // 8 points per thread

typedef unsigned long long u64;

__global__ __launch_bounds__(NTHREADS, 4)
void fps_kernel(const float* __restrict__ points,
                float* __restrict__ out,
                u64* __restrict__ slots, int M)
{
  const int bid  = blockIdx.x;
  // XCD swizzle: blocks with same (bid & 7) land on the same XCD (round-robin).
  const int xcd  = bid & 7;
  const int ord  = bid >> 3;          // 0..31 within XCD
  const int batch = xcd * 2 + (ord >> 4);
  const int sub   = ord & 15;
  const int tid  = threadIdx.x;
  const int wave = tid >> 6;
  const int lane = tid & 63;

  const float* __restrict__ px = points + (size_t)batch * 3 * NPTS;
  const float* __restrict__ py = px + NPTS;
  const float* __restrict__ pz = px + 2 * NPTS;
  float* outb  = out + (size_t)batch * 3 * M;
  u64* bslots  = slots + (size_t)batch * 2 * SUBBLOCKS;

  const int base = sub * (NPTS / SUBBLOCKS) + tid;   // thread's first point

  // Per-thread state fully in registers: 8 x (x,y,z,dist) = 32 VGPRs.
  float x[PPT], y[PPT], z[PPT], dist[PPT];
#pragma unroll
  for (int i = 0; i < PPT; ++i) {
    int idx = base + (i << 10);
    x[i] = px[idx];
    y[i] = py[idx];
    z[i] = pz[idx];
    dist[i] = __builtin_inff();
  }

  __shared__ u64 wkeys[NTHREADS / 64];
  __shared__ u64 winner_s;

  // Selection 0 is index 0 by convention.
  if (sub == 0 && tid == 0) {
    outb[0]     = px[0];
    outb[M]     = py[0];
    outb[2 * M] = pz[0];
  }

  int sel = 0;
  for (int t = 1; t < M; ++t) {
    // Centroid = previously selected point (uniform; broadcast loads, L2-hot).
    float cx = px[sel], cy = py[sel], cz = pz[sel];

    float best = -1.0f;
    int bidx = 0;
#pragma unroll
    for (int i = 0; i < PPT; ++i) {
      float dx = __fsub_rn(x[i], cx);
      float dy = __fsub_rn(y[i], cy);
      float dz = __fsub_rn(z[i], cz);
      // XLA-CPU reduce chain with FMA contraction:
      //   acc = dx*dx; acc = fma(dy,dy,acc); acc = fma(dz,dz,acc)
      float d  = __builtin_fmaf(dz, dz,
                   __builtin_fmaf(dy, dy, __fmul_rn(dx, dx)));
      float nd = dist[i] < d ? dist[i] : d;   // np.minimum (no NaNs here)
      dist[i] = nd;
      // strict '>' keeps the smallest index on ties (i ascending => idx ascending)
      if (nd > best) { best = nd; bidx = base + (i << 10); }
    }

    // Pack: [tag @49][distBits:32 @17][invIdx:17 @0].
    // Non-negative f32 bits are order-preserving; invIdx breaks ties toward
    // the SMALLEST index (numpy argmax = first occurrence).
    u64 key = ((u64)__float_as_uint(best) << 17) | (u64)((NPTS - 1) - bidx);

    // Wave (64-lane) butterfly max-reduce.
#pragma unroll
    for (int m = 32; m >= 1; m >>= 1) {
      u64 o = __shfl_xor(key, m, 64);
      key = o > key ? o : key;
    }
    if (lane == 0) wkeys[wave] = key;
    __syncthreads();

    if (wave == 0) {
      // Reduce the 16 wave keys (lanes 0..15).
      u64 k = (lane < (NTHREADS / 64)) ? wkeys[lane] : 0;
#pragma unroll
      for (int m = 8; m >= 1; m >>= 1) {
        u64 o = __shfl_xor(k, m, 64);
        k = o > k ? o : k;
      }
      // Publish this block's key, tagged with iteration t, in parity buffer.
      u64* parity = bslots + (size_t)(t & 1) * SUBBLOCKS;
      if (lane == 0) {
        __hip_atomic_store(parity + sub, ((u64)t << 49) | k,
                           __ATOMIC_RELEASE, __HIP_MEMORY_SCOPE_AGENT);
      }
      // Spin: lane j waits for sub-block j's key for this iteration.
      u64 v = 0;
      if (lane < SUBBLOCKS) {
        const u64* p = parity + lane;
        do {
          v = __hip_atomic_load(p, __ATOMIC_ACQUIRE, __HIP_MEMORY_SCOPE_AGENT);
        } while ((unsigned)(v >> 49) != (unsigned)t);
      }
#pragma unroll
      for (int m = 8; m >= 1; m >>= 1) {
        u64 o = __shfl_xor(v, m, 64);
        v = o > v ? o : v;
      }
      if (lane == 0) winner_s = v;
    }
    __syncthreads();

    u64 wk = winner_s;
    sel = (NPTS - 1) - (int)(wk & 0x1FFFF);

    if (sub == 0 && tid == 0) {
      outb[t]         = px[sel];
      outb[M + t]     = py[sel];
      outb[2 * M + t] = pz[sel];
    }
  }
}

extern "C" void kernel_launch(void* const* d_in, const int* in_sizes, int n_in,
                              void* d_out, int out_size, void* d_ws, size_t ws_size,
                              hipStream_t stream) {
  (void)in_sizes; (void)n_in; (void)ws_size;
  const float* points = (const float*)d_in[0];
  float* out = (float*)d_out;
  u64* slots = (u64*)d_ws;
  const int M = out_size / (NBATCH * 3);   // 2048

  // Zero the barrier slots (tags must not collide with 1..M-1). Memset nodes
  // are graph-capturable; runs before the kernel on `stream` every call.
  hipMemsetAsync(d_ws, 0, (size_t)NBATCH * 2 * SUBBLOCKS * sizeof(u64), stream);

  hipLaunchKernelGGL(fps_kernel, dim3(NBATCH * SUBBLOCKS), dim3(NTHREADS), 0,
                     stream, points, out, slots, M);
}